// Round 8
// baseline (392.446 us; speedup 1.0000x reference)
//
#include <hip/hip_runtime.h>
#include <float.h>
#include <math.h>

#define NROWS 65536
#define DIM 256
#define NCODES 2048

typedef _Float16 f16x8 __attribute__((ext_vector_type(8)));
typedef float    f32x4 __attribute__((ext_vector_type(4)));

__device__ __forceinline__ void ld16(const void* g, void* l) {
    __builtin_amdgcn_global_load_lds(
        (__attribute__((address_space(1))) void*)g,
        (__attribute__((address_space(3))) void*)l, 16, 0, 0);
}

// -------- fused pre-pass: split z/cb to interleaved (hi|lo) fp16 + cbsq + zeroing -----
// blocks [0,8192): z split ; [8192,8448): cb split ; [8448,8960): cbsq (identical
// math/order to the verified cbsq kernel). Block 8448 additionally zeros
// usage/accum/ticket (replaces hipMemsetAsync).
// pk layout: row stride 512 halves = [h0..h255 | l0..l255]  (1 KB per row) so
// out-row r (1 KB fp32) overlaps exactly row r's own h/l scratch.
__global__ void split_all_kernel(const float* __restrict__ z, _Float16* __restrict__ zpk,
                                 const float* __restrict__ cb, _Float16* __restrict__ wpk,
                                 float* __restrict__ cbsq, int* __restrict__ usage,
                                 float* __restrict__ accum, int* __restrict__ ticket) {
    const int bid = blockIdx.x;
    const int t   = threadIdx.x;
    if (bid < 8448) {
        const float* x; _Float16* pk; int i;
        if (bid < 8192) { x = z;  pk = zpk; i = (bid * 256 + t) * 8; }
        else            { x = cb; pk = wpk; i = ((bid - 8192) * 256 + t) * 8; }
        int row = i >> 8, d = i & 255;
        float4 a = *(const float4*)(x + i);
        float4 b = *(const float4*)(x + i + 4);
        float v[8] = {a.x, a.y, a.z, a.w, b.x, b.y, b.z, b.w};
        _Float16 h[8], l[8];
        #pragma unroll
        for (int k = 0; k < 8; k++) {
            h[k] = (_Float16)v[k];
            l[k] = (_Float16)(v[k] - (float)h[k]);   // v - (float)h is exact in fp32
        }
        *(f16x8*)(pk + (size_t)row * 512 + d)       = *(const f16x8*)h;
        *(f16x8*)(pk + (size_t)row * 512 + 256 + d) = *(const f16x8*)l;
    } else {
        // codebook squared norms (fp32 exact, bit-identical order): one wave/code
        int wid  = ((bid - 8448) * 256 + t) >> 6;
        int lane = t & 63;
        const float4* c4 = (const float4*)cb;
        float4 v = c4[wid * 64 + lane];
        float s = v.x * v.x + v.y * v.y + v.z * v.z + v.w * v.w;
        #pragma unroll
        for (int m = 32; m >= 1; m >>= 1) s += __shfl_xor(s, m, 64);
        if (lane == 0) cbsq[wid] = s;
        if (bid == 8448) {
            #pragma unroll
            for (int u = 0; u < 8; u++) usage[t * 8 + u] = 0;
            if (t == 0) { *accum = 0.0f; *ticket = 0; }
        }
    }
}

// -------- MFMA argmin + fused gather + last-block finalize: 256 x 512 thr --------
// Main loop identical to the verified 198.7us kernel (same LDS layout, swizzle,
// vmcnt(8) double-buffer, MFMA order). After the index merge: software-pipelined
// gather/STE/commitment/histogram tail; the last block to finish computes the
// scalar outputs (device-scope atomic reads -> XCD-coherent).
// dot = zh*wh + zh*wl + zl*wh  (fp16 split; zl*wl term ~2^-24, dropped)
__global__ __launch_bounds__(512, 2)
void argmin_kernel(const _Float16* __restrict__ zpk, const _Float16* __restrict__ wpk,
                   const float* __restrict__ cbsq, float* __restrict__ idx_out,
                   const float* __restrict__ z, const float* __restrict__ cb,
                   float* __restrict__ out, int* __restrict__ usage,
                   float* __restrict__ accum, int* __restrict__ ticket,
                   float* __restrict__ out2) {
    __shared__ _Float16 Ah[2][256 * 32];   // 2 x 16 KB
    __shared__ _Float16 Al[2][256 * 32];   // 2 x 16 KB
    __shared__ _Float16 Bh[2][256 * 32];   // 2 x 16 KB
    __shared__ _Float16 Bl[2][256 * 32];   // 2 x 16 KB
    __shared__ float cbsq_lds[NCODES];     // 8 KB (reused as finalize scratch)
    __shared__ int amLast;

    const int t    = threadIdx.x;
    const int wave = t >> 6;
    const int lane = t & 63;
    const int quad = lane >> 4;
    const int l15  = lane & 15;
    const int wr0  = (wave >> 1) * 64;    // wave row offset within block tile
    const int wc0  = (wave & 1) * 128;    // wave code offset within chunk
    const int row0 = blockIdx.x * 256;

    // swizzled read offset (granule of 8 halves): pos = quad ^ ((row>>1)&3)
    const int p8 = (quad ^ ((l15 >> 1) & 3)) * 8;

    // stage cbsq into LDS: 512 thr x 16 B = 8 KB
    ld16(cbsq + t * 4, &cbsq_lds[t * 4]);

    // prologue: stage step 0 (cc=0, kc=0) into buffer 0 (8 ld16/thread)
    #pragma unroll
    for (int it = 0; it < 2; it++) {
        int s = it * 512 + t;
        int r = s >> 2;
        int g = (s & 3) ^ ((r >> 1) & 3);
        size_t offa = (size_t)(row0 + r) * 512 + g * 8;
        size_t offb = (size_t)r * 512 + g * 8;
        ld16(zpk + offa,       &Ah[0][s * 8]);
        ld16(zpk + offa + 256, &Al[0][s * 8]);
        ld16(wpk + offb,       &Bh[0][s * 8]);
        ld16(wpk + offb + 256, &Bl[0][s * 8]);
    }

    float bd[16];
    int   bi[16];
    #pragma unroll
    for (int s = 0; s < 16; s++) { bd[s] = FLT_MAX; bi[s] = 0; }

    f32x4 acc[4][8];

    #pragma unroll 2
    for (int tt = 0; tt < 64; ++tt) {
        const int kc  = tt & 7;
        const int cur = tt & 1;

        // stage step tt+1 into the other buffer, then wait only for step tt's
        // 8 loads (issued one full compute-phase ago) -> latency hidden.
        if (tt < 63) {
            const int t1 = tt + 1;
            const int cc1 = t1 >> 3, kc1 = t1 & 7, nb = t1 & 1;
            #pragma unroll
            for (int it = 0; it < 2; it++) {
                int s = it * 512 + t;
                int r = s >> 2;
                int g = (s & 3) ^ ((r >> 1) & 3);
                size_t offa = (size_t)(row0 + r) * 512 + kc1 * 32 + g * 8;
                size_t offb = (size_t)(cc1 * 256 + r) * 512 + kc1 * 32 + g * 8;
                ld16(zpk + offa,       &Ah[nb][s * 8]);
                ld16(zpk + offa + 256, &Al[nb][s * 8]);
                ld16(wpk + offb,       &Bh[nb][s * 8]);
                ld16(wpk + offb + 256, &Bl[nb][s * 8]);
            }
            asm volatile("s_waitcnt vmcnt(8)" ::: "memory");
        } else {
            asm volatile("s_waitcnt vmcnt(0)" ::: "memory");
        }
        __builtin_amdgcn_s_barrier();
        asm volatile("" ::: "memory");
        __builtin_amdgcn_sched_barrier(0);   // do not hoist ds_reads above barrier

        if (kc == 0) {
            #pragma unroll
            for (int i = 0; i < 4; i++)
                #pragma unroll
                for (int j = 0; j < 8; j++) acc[i][j] = (f32x4){0.f, 0.f, 0.f, 0.f};
        }

        const _Float16* Ahc = &Ah[cur][0];
        const _Float16* Alc = &Al[cur][0];
        const _Float16* Bhc = &Bh[cur][0];
        const _Float16* Blc = &Bl[cur][0];

        f16x8 ah[4], al[4];
        #pragma unroll
        for (int i = 0; i < 4; i++) {
            int off = (wr0 + i * 16 + l15) * 32 + p8;
            ah[i] = *(const f16x8*)&Ahc[off];
            al[i] = *(const f16x8*)&Alc[off];
        }
        __builtin_amdgcn_s_setprio(1);
        #pragma unroll
        for (int j = 0; j < 8; j++) {
            int offb = (wc0 + j * 16 + l15) * 32 + p8;
            f16x8 bh = *(const f16x8*)&Bhc[offb];
            f16x8 bl = *(const f16x8*)&Blc[offb];
            #pragma unroll
            for (int i = 0; i < 4; i++) {
                acc[i][j] = __builtin_amdgcn_mfma_f32_16x16x32_f16(ah[i], bh, acc[i][j], 0, 0, 0);
                acc[i][j] = __builtin_amdgcn_mfma_f32_16x16x32_f16(ah[i], bl, acc[i][j], 0, 0, 0);
                acc[i][j] = __builtin_amdgcn_mfma_f32_16x16x32_f16(al[i], bh, acc[i][j], 0, 0, 0);
            }
        }
        __builtin_amdgcn_s_setprio(0);

        // epilogue each 8th step: d = cbsq[c] - 2*dot ; codes ascend -> first-min kept
        if (kc == 7) {
            const int cc = tt >> 3;
            #pragma unroll
            for (int j = 0; j < 8; j++) {
                int c = cc * 256 + wc0 + j * 16 + l15;
                float csq = cbsq_lds[c];
                #pragma unroll
                for (int i = 0; i < 4; i++) {
                    #pragma unroll
                    for (int r = 0; r < 4; r++) {
                        float d = fmaf(-2.0f, acc[i][j][r], csq);
                        int s = i * 4 + r;
                        if (d < bd[s]) { bd[s] = d; bi[s] = c; }
                    }
                }
            }
        }
        asm volatile("" ::: "memory");
        __builtin_amdgcn_s_barrier();
    }

    // reduce across the 16 lanes (l15) holding the same rows; tie -> smaller index
    #pragma unroll
    for (int m = 1; m <= 8; m <<= 1) {
        #pragma unroll
        for (int s = 0; s < 16; s++) {
            float od = __shfl_xor(bd[s], m, 64);
            int   oi = __shfl_xor(bi[s], m, 64);
            if (od < bd[s] || (od == bd[s] && oi < bi[s])) { bd[s] = od; bi[s] = oi; }
        }
    }
    // overlay reduction arrays on A buffers (all staging complete after the loop)
    float* rD = (float*)&Ah[0][0];   // [2][256]
    int*   rI = (int*)&Al[0][0];     // [2][256]
    int*   sI = (int*)&Bh[0][0];     // [256] final per-row index
    if (l15 == 0) {
        const int wc = wave & 1;
        #pragma unroll
        for (int i = 0; i < 4; i++) {
            #pragma unroll
            for (int r = 0; r < 4; r++) {
                int row = wr0 + i * 16 + quad * 4 + r;
                rD[wc * 256 + row] = bd[i * 4 + r];
                rI[wc * 256 + row] = bi[i * 4 + r];
            }
        }
    }
    __syncthreads();
    if (t < 256) {
        float d0 = rD[t];       int i0 = rI[t];
        float d1 = rD[256 + t]; int i1 = rI[256 + t];
        int best = (d1 < d0 || (d1 == d0 && i1 < i0)) ? i1 : i0;
        sI[t] = best;
        idx_out[row0 + t] = (float)best;
    }
    __syncthreads();

    // -------- fused gather + STE + commitment partial + histogram (pipelined) -----
    // All zpk reads for this block are complete (vmcnt(0) + barriers above), and
    // out rows [row0,row0+256) overlap only this block's own zpk rows.
    {
        const float4* z4  = (const float4*)z;
        const float4* cb4 = (const float4*)cb;
        float4* o4 = (float4*)out;
        float local = 0.0f;

        float4 zvA[4], wA[4]; int idA[4];
        float4 zvB[4], wB[4]; int idB[4];

        #define TLOAD(B, ZV, W, ID)                                     \
            _Pragma("unroll")                                           \
            for (int u = 0; u < 4; u++) {                               \
                int rr = wave + 8 * ((B) * 4 + u);                      \
                ID[u] = sI[rr];                                         \
                ZV[u] = z4[(size_t)(row0 + rr) * 64 + lane];            \
                W[u]  = cb4[(size_t)ID[u] * 64 + lane];                 \
            }
        #define TCOMP(B, ZV, W, ID)                                     \
            _Pragma("unroll")                                           \
            for (int u = 0; u < 4; u++) {                               \
                int rr = wave + 8 * ((B) * 4 + u);                      \
                float4 d, o;                                            \
                d.x = W[u].x - ZV[u].x; d.y = W[u].y - ZV[u].y;         \
                d.z = W[u].z - ZV[u].z; d.w = W[u].w - ZV[u].w;         \
                o.x = ZV[u].x + d.x; o.y = ZV[u].y + d.y;               \
                o.z = ZV[u].z + d.z; o.w = ZV[u].w + d.w;               \
                o4[(size_t)(row0 + rr) * 64 + lane] = o;                \
                local = fmaf(d.x, d.x, local);                          \
                local = fmaf(d.y, d.y, local);                          \
                local = fmaf(d.z, d.z, local);                          \
                local = fmaf(d.w, d.w, local);                          \
                if (lane == 0) atomicAdd(&usage[ID[u]], 1);             \
            }

        TLOAD(0, zvA, wA, idA)
        #pragma unroll
        for (int b = 0; b < 8; b += 2) {
            if (b + 1 < 8) TLOAD(b + 1, zvB, wB, idB)
            TCOMP(b, zvA, wA, idA)
            if (b + 2 < 8) TLOAD(b + 2, zvA, wA, idA)
            if (b + 1 < 8) TCOMP(b + 1, zvB, wB, idB)
        }
        #undef TLOAD
        #undef TCOMP

        #pragma unroll
        for (int m = 32; m >= 1; m >>= 1) local += __shfl_xor(local, m, 64);
        if (lane == 0) atomicAdd(accum, local);
    }

    // -------- last-block finalize: commitment mean + entropy loss --------
    __threadfence();                       // release my usage/accum atomics
    __syncthreads();
    if (t == 0) amLast = (atomicAdd(ticket, 1) == 255) ? 1 : 0;
    __syncthreads();
    if (amLast) {
        float* red = cbsq_lds;             // reuse (cbsq no longer needed)
        if (t < 256) {
            float e = 0.0f;
            for (int b = t; b < NCODES; b += 256) {
                // atomic read -> device-coherent across XCD L2s
                float p = (float)atomicAdd(&usage[b], 0) * (1.0f / 65536.0f);
                e -= p * logf(p + 1e-10f);
            }
            red[t] = e;
        }
        __syncthreads();
        if (t == 0) {
            float s = 0.0f;
            for (int k = 0; k < 256; k++) s += red[k];
            out2[0] = atomicAdd(accum, 0.0f) / 16777216.0f;
            out2[1] = logf(2048.0f) - s;
        }
    }
}

extern "C" void kernel_launch(void* const* d_in, const int* in_sizes, int n_in,
                              void* d_out, int out_size, void* d_ws, size_t ws_size,
                              hipStream_t stream) {
    const float* z  = (const float*)d_in[0];
    const float* cb = (const float*)d_in[1];

    float* out   = (float*)d_out;
    float* idx_f = out + (size_t)NROWS * DIM;   // float offset 16777216 (byte 67108864)
    float* out2  = idx_f + NROWS;

    // z hi/lo scratch lives in the zq output region (exactly 64 MiB) with an
    // INTERLEAVED per-row layout [h(256)|l(256)] so the fused gather's out-row
    // write clobbers only the owning block's own rows.
    _Float16* zpk = (_Float16*)d_out;

    // ws: wpk 2MB (interleaved) | cbsq 8KB | usage 8KB | accum 4B | ticket 4B
    _Float16* wpk  = (_Float16*)d_ws;
    float*    cbsq = (float*)((char*)d_ws + 2097152);
    int*      usage= (int*)((char*)d_ws + 2105344);
    float*    accum= (float*)((char*)d_ws + 2113536);
    int*      ticket=(int*)((char*)d_ws + 2113540);

    split_all_kernel<<<8960, 256, 0, stream>>>(z, zpk, cb, wpk, cbsq, usage, accum, ticket);
    argmin_kernel<<<256, 512, 0, stream>>>(zpk, wpk, cbsq, idx_f, z, cb, out, usage,
                                           accum, ticket, out2);
}

// Round 10
// 343.423 us; speedup vs baseline: 1.1428x; 1.1428x over previous
//
#include <hip/hip_runtime.h>
#include <float.h>
#include <math.h>

#define NROWS 65536
#define DIM 256
#define NCODES 2048

typedef _Float16 f16x8 __attribute__((ext_vector_type(8)));
typedef float    f32x4 __attribute__((ext_vector_type(4)));

__device__ __forceinline__ void ld16(const void* g, void* l) {
    __builtin_amdgcn_global_load_lds(
        (__attribute__((address_space(1))) void*)g,
        (__attribute__((address_space(3))) void*)l, 16, 0, 0);
}

// -------- fused pre-pass: split z/cb to interleaved (hi|lo) fp16 + cbsq + zeroing -----
// blocks [0,8192): z split ; [8192,8448): cb split ; [8448,8960): cbsq (identical
// math/order to the verified cbsq kernel). Block 8448 additionally zeros
// usage/accum/ticket (replaces hipMemsetAsync).
// pk layout: row stride 512 halves = [h0..h255 | l0..l255]  (1 KB per row) so
// out-row r (1 KB fp32) overlaps exactly row r's own h/l scratch.
__global__ void split_all_kernel(const float* __restrict__ z, _Float16* __restrict__ zpk,
                                 const float* __restrict__ cb, _Float16* __restrict__ wpk,
                                 float* __restrict__ cbsq, int* __restrict__ usage,
                                 float* __restrict__ accum, int* __restrict__ ticket) {
    const int bid = blockIdx.x;
    const int t   = threadIdx.x;
    if (bid < 8448) {
        const float* x; _Float16* pk; int i;
        if (bid < 8192) { x = z;  pk = zpk; i = (bid * 256 + t) * 8; }
        else            { x = cb; pk = wpk; i = ((bid - 8192) * 256 + t) * 8; }
        int row = i >> 8, d = i & 255;
        float4 a = *(const float4*)(x + i);
        float4 b = *(const float4*)(x + i + 4);
        float v[8] = {a.x, a.y, a.z, a.w, b.x, b.y, b.z, b.w};
        _Float16 h[8], l[8];
        #pragma unroll
        for (int k = 0; k < 8; k++) {
            h[k] = (_Float16)v[k];
            l[k] = (_Float16)(v[k] - (float)h[k]);   // v - (float)h is exact in fp32
        }
        *(f16x8*)(pk + (size_t)row * 512 + d)       = *(const f16x8*)h;
        *(f16x8*)(pk + (size_t)row * 512 + 256 + d) = *(const f16x8*)l;
    } else {
        // codebook squared norms (fp32 exact, bit-identical order): one wave/code
        int wid  = ((bid - 8448) * 256 + t) >> 6;
        int lane = t & 63;
        const float4* c4 = (const float4*)cb;
        float4 v = c4[wid * 64 + lane];
        float s = v.x * v.x + v.y * v.y + v.z * v.z + v.w * v.w;
        #pragma unroll
        for (int m = 32; m >= 1; m >>= 1) s += __shfl_xor(s, m, 64);
        if (lane == 0) cbsq[wid] = s;
        if (bid == 8448) {
            #pragma unroll
            for (int u = 0; u < 8; u++) usage[t * 8 + u] = 0;
            if (t == 0) { *accum = 0.0f; *ticket = 0; }
        }
    }
}

// -------- MFMA argmin + fused gather + last-block finalize: 256 x 512 thr --------
// Main loop identical to the verified 198.7us kernel (same LDS layout, swizzle,
// vmcnt(8) double-buffer, MFMA order). After the index merge: simple per-wave
// gather/STE/commitment/histogram tail (R7-verified, 44us); the last block to
// finish computes the scalar outputs. NO __threadfence: usage/accum are written
// with device-scope atomics (XCD-coherent once complete); each wave drains its
// vmcnt before the ticket barrier, so ticket==255 implies all atomics landed.
// dot = zh*wh + zh*wl + zl*wh  (fp16 split; zl*wl term ~2^-24, dropped)
__global__ __launch_bounds__(512, 2)
void argmin_kernel(const _Float16* __restrict__ zpk, const _Float16* __restrict__ wpk,
                   const float* __restrict__ cbsq, float* __restrict__ idx_out,
                   const float* __restrict__ z, const float* __restrict__ cb,
                   float* __restrict__ out, int* __restrict__ usage,
                   float* __restrict__ accum, int* __restrict__ ticket,
                   float* __restrict__ out2) {
    __shared__ _Float16 Ah[2][256 * 32];   // 2 x 16 KB
    __shared__ _Float16 Al[2][256 * 32];   // 2 x 16 KB
    __shared__ _Float16 Bh[2][256 * 32];   // 2 x 16 KB
    __shared__ _Float16 Bl[2][256 * 32];   // 2 x 16 KB
    __shared__ float cbsq_lds[NCODES];     // 8 KB (reused as finalize scratch)
    __shared__ int amLast;

    const int t    = threadIdx.x;
    const int wave = t >> 6;
    const int lane = t & 63;
    const int quad = lane >> 4;
    const int l15  = lane & 15;
    const int wr0  = (wave >> 1) * 64;    // wave row offset within block tile
    const int wc0  = (wave & 1) * 128;    // wave code offset within chunk
    const int row0 = blockIdx.x * 256;

    // swizzled read offset (granule of 8 halves): pos = quad ^ ((row>>1)&3)
    const int p8 = (quad ^ ((l15 >> 1) & 3)) * 8;

    // stage cbsq into LDS: 512 thr x 16 B = 8 KB
    ld16(cbsq + t * 4, &cbsq_lds[t * 4]);

    // prologue: stage step 0 (cc=0, kc=0) into buffer 0 (8 ld16/thread)
    #pragma unroll
    for (int it = 0; it < 2; it++) {
        int s = it * 512 + t;
        int r = s >> 2;
        int g = (s & 3) ^ ((r >> 1) & 3);
        size_t offa = (size_t)(row0 + r) * 512 + g * 8;
        size_t offb = (size_t)r * 512 + g * 8;
        ld16(zpk + offa,       &Ah[0][s * 8]);
        ld16(zpk + offa + 256, &Al[0][s * 8]);
        ld16(wpk + offb,       &Bh[0][s * 8]);
        ld16(wpk + offb + 256, &Bl[0][s * 8]);
    }

    float bd[16];
    int   bi[16];
    #pragma unroll
    for (int s = 0; s < 16; s++) { bd[s] = FLT_MAX; bi[s] = 0; }

    f32x4 acc[4][8];

    #pragma unroll 2
    for (int tt = 0; tt < 64; ++tt) {
        const int kc  = tt & 7;
        const int cur = tt & 1;

        // stage step tt+1 into the other buffer, then wait only for step tt's
        // 8 loads (issued one full compute-phase ago) -> latency hidden.
        if (tt < 63) {
            const int t1 = tt + 1;
            const int cc1 = t1 >> 3, kc1 = t1 & 7, nb = t1 & 1;
            #pragma unroll
            for (int it = 0; it < 2; it++) {
                int s = it * 512 + t;
                int r = s >> 2;
                int g = (s & 3) ^ ((r >> 1) & 3);
                size_t offa = (size_t)(row0 + r) * 512 + kc1 * 32 + g * 8;
                size_t offb = (size_t)(cc1 * 256 + r) * 512 + kc1 * 32 + g * 8;
                ld16(zpk + offa,       &Ah[nb][s * 8]);
                ld16(zpk + offa + 256, &Al[nb][s * 8]);
                ld16(wpk + offb,       &Bh[nb][s * 8]);
                ld16(wpk + offb + 256, &Bl[nb][s * 8]);
            }
            asm volatile("s_waitcnt vmcnt(8)" ::: "memory");
        } else {
            asm volatile("s_waitcnt vmcnt(0)" ::: "memory");
        }
        __builtin_amdgcn_s_barrier();
        asm volatile("" ::: "memory");
        __builtin_amdgcn_sched_barrier(0);   // do not hoist ds_reads above barrier

        if (kc == 0) {
            #pragma unroll
            for (int i = 0; i < 4; i++)
                #pragma unroll
                for (int j = 0; j < 8; j++) acc[i][j] = (f32x4){0.f, 0.f, 0.f, 0.f};
        }

        const _Float16* Ahc = &Ah[cur][0];
        const _Float16* Alc = &Al[cur][0];
        const _Float16* Bhc = &Bh[cur][0];
        const _Float16* Blc = &Bl[cur][0];

        f16x8 ah[4], al[4];
        #pragma unroll
        for (int i = 0; i < 4; i++) {
            int off = (wr0 + i * 16 + l15) * 32 + p8;
            ah[i] = *(const f16x8*)&Ahc[off];
            al[i] = *(const f16x8*)&Alc[off];
        }
        __builtin_amdgcn_s_setprio(1);
        #pragma unroll
        for (int j = 0; j < 8; j++) {
            int offb = (wc0 + j * 16 + l15) * 32 + p8;
            f16x8 bh = *(const f16x8*)&Bhc[offb];
            f16x8 bl = *(const f16x8*)&Blc[offb];
            #pragma unroll
            for (int i = 0; i < 4; i++) {
                acc[i][j] = __builtin_amdgcn_mfma_f32_16x16x32_f16(ah[i], bh, acc[i][j], 0, 0, 0);
                acc[i][j] = __builtin_amdgcn_mfma_f32_16x16x32_f16(ah[i], bl, acc[i][j], 0, 0, 0);
                acc[i][j] = __builtin_amdgcn_mfma_f32_16x16x32_f16(al[i], bh, acc[i][j], 0, 0, 0);
            }
        }
        __builtin_amdgcn_s_setprio(0);

        // epilogue each 8th step: d = cbsq[c] - 2*dot ; codes ascend -> first-min kept
        if (kc == 7) {
            const int cc = tt >> 3;
            #pragma unroll
            for (int j = 0; j < 8; j++) {
                int c = cc * 256 + wc0 + j * 16 + l15;
                float csq = cbsq_lds[c];
                #pragma unroll
                for (int i = 0; i < 4; i++) {
                    #pragma unroll
                    for (int r = 0; r < 4; r++) {
                        float d = fmaf(-2.0f, acc[i][j][r], csq);
                        int s = i * 4 + r;
                        if (d < bd[s]) { bd[s] = d; bi[s] = c; }
                    }
                }
            }
        }
        asm volatile("" ::: "memory");
        __builtin_amdgcn_s_barrier();
    }

    // reduce across the 16 lanes (l15) holding the same rows; tie -> smaller index
    #pragma unroll
    for (int m = 1; m <= 8; m <<= 1) {
        #pragma unroll
        for (int s = 0; s < 16; s++) {
            float od = __shfl_xor(bd[s], m, 64);
            int   oi = __shfl_xor(bi[s], m, 64);
            if (od < bd[s] || (od == bd[s] && oi < bi[s])) { bd[s] = od; bi[s] = oi; }
        }
    }
    // overlay reduction arrays on A buffers (all staging complete after the loop)
    float* rD = (float*)&Ah[0][0];   // [2][256]
    int*   rI = (int*)&Al[0][0];     // [2][256]
    int*   sI = (int*)&Bh[0][0];     // [256] final per-row index
    if (l15 == 0) {
        const int wc = wave & 1;
        #pragma unroll
        for (int i = 0; i < 4; i++) {
            #pragma unroll
            for (int r = 0; r < 4; r++) {
                int row = wr0 + i * 16 + quad * 4 + r;
                rD[wc * 256 + row] = bd[i * 4 + r];
                rI[wc * 256 + row] = bi[i * 4 + r];
            }
        }
    }
    __syncthreads();
    if (t < 256) {
        float d0 = rD[t];       int i0 = rI[t];
        float d1 = rD[256 + t]; int i1 = rI[256 + t];
        int best = (d1 < d0 || (d1 == d0 && i1 < i0)) ? i1 : i0;
        sI[t] = best;
        idx_out[row0 + t] = (float)best;
    }
    __syncthreads();

    // -------- fused gather + STE + commitment partial + histogram (simple, R7) -----
    // All zpk reads for this block are complete (vmcnt(0) + barriers above), and
    // out rows [row0,row0+256) overlap only this block's own zpk rows.
    {
        const float4* z4  = (const float4*)z;
        const float4* cb4 = (const float4*)cb;
        float4* o4 = (float4*)out;
        float local = 0.0f;
        for (int rr = wave; rr < 256; rr += 8) {
            int idx = sI[rr];
            size_t grow = (size_t)(row0 + rr);
            float4 zv = z4[grow * 64 + lane];
            float4 w  = cb4[(size_t)idx * 64 + lane];
            float4 d, o;
            d.x = w.x - zv.x; d.y = w.y - zv.y; d.z = w.z - zv.z; d.w = w.w - zv.w;
            o.x = zv.x + d.x; o.y = zv.y + d.y; o.z = zv.z + d.z; o.w = zv.w + d.w;
            o4[grow * 64 + lane] = o;
            local = fmaf(d.x, d.x, local);
            local = fmaf(d.y, d.y, local);
            local = fmaf(d.z, d.z, local);
            local = fmaf(d.w, d.w, local);
            if (lane == 0) atomicAdd(&usage[idx], 1);
        }
        #pragma unroll
        for (int m = 32; m >= 1; m >>= 1) local += __shfl_xor(local, m, 64);
        if (lane == 0) atomicAdd(accum, local);
    }

    // -------- last-block finalize: commitment mean + entropy loss --------
    // Drain this wave's outstanding (atomic) VMEM ops, then block barrier
    // (which itself drains all waves), then one device-scope ticket RMW.
    asm volatile("s_waitcnt vmcnt(0)" ::: "memory");
    __syncthreads();
    if (t == 0) amLast = (atomicAdd(ticket, 1) == 255) ? 1 : 0;
    __syncthreads();
    if (amLast) {
        float* red = cbsq_lds;             // reuse (cbsq no longer needed)
        if (t < 256) {
            float e = 0.0f;
            for (int b = t; b < NCODES; b += 256) {
                // atomic read -> device-coherent across XCD L2s
                float p = (float)atomicAdd(&usage[b], 0) * (1.0f / 65536.0f);
                e -= p * logf(p + 1e-10f);
            }
            red[t] = e;
        }
        __syncthreads();
        if (t == 0) {
            float s = 0.0f;
            for (int k = 0; k < 256; k++) s += red[k];
            out2[0] = atomicAdd(accum, 0.0f) / 16777216.0f;
            out2[1] = logf(2048.0f) - s;
        }
    }
}

extern "C" void kernel_launch(void* const* d_in, const int* in_sizes, int n_in,
                              void* d_out, int out_size, void* d_ws, size_t ws_size,
                              hipStream_t stream) {
    const float* z  = (const float*)d_in[0];
    const float* cb = (const float*)d_in[1];

    float* out   = (float*)d_out;
    float* idx_f = out + (size_t)NROWS * DIM;   // float offset 16777216 (byte 67108864)
    float* out2  = idx_f + NROWS;

    // z hi/lo scratch lives in the zq output region (exactly 64 MiB) with an
    // INTERLEAVED per-row layout [h(256)|l(256)] so the fused gather's out-row
    // write clobbers only the owning block's own rows.
    _Float16* zpk = (_Float16*)d_out;

    // ws: wpk 2MB (interleaved) | cbsq 8KB | usage 8KB | accum 4B | ticket 4B
    _Float16* wpk  = (_Float16*)d_ws;
    float*    cbsq = (float*)((char*)d_ws + 2097152);
    int*      usage= (int*)((char*)d_ws + 2105344);
    float*    accum= (float*)((char*)d_ws + 2113536);
    int*      ticket=(int*)((char*)d_ws + 2113540);

    split_all_kernel<<<8960, 256, 0, stream>>>(z, zpk, cb, wpk, cbsq, usage, accum, ticket);
    argmin_kernel<<<256, 512, 0, stream>>>(zpk, wpk, cbsq, idx_f, z, cb, out, usage,
                                           accum, ticket, out2);
}

// Round 11
// 334.260 us; speedup vs baseline: 1.1741x; 1.0274x over previous
//
#include <hip/hip_runtime.h>
#include <float.h>
#include <math.h>

#define NROWS 65536
#define DIM 256
#define NCODES 2048

typedef _Float16 f16x8 __attribute__((ext_vector_type(8)));
typedef float    f32x4 __attribute__((ext_vector_type(4)));

__device__ __forceinline__ void ld16(const void* g, void* l) {
    __builtin_amdgcn_global_load_lds(
        (__attribute__((address_space(1))) void*)g,
        (__attribute__((address_space(3))) void*)l, 16, 0, 0);
}

// -------- prep: cb split to interleaved (hi|lo) fp16 + cbsq + zeroing --------
// blocks [0,256): cb split ; [256,768): cbsq (identical math/order to the
// verified cbsq kernel). Block 256 additionally zeros usage/accum/ticket.
// wpk layout: row stride 512 halves = [h0..h255 | l0..l255] (1 KB per code).
__global__ void prep_kernel(const float* __restrict__ cb, _Float16* __restrict__ wpk,
                            float* __restrict__ cbsq, int* __restrict__ usage,
                            float* __restrict__ accum, int* __restrict__ ticket) {
    const int bid = blockIdx.x;
    const int t   = threadIdx.x;
    if (bid < 256) {
        int i = (bid * 256 + t) * 8;
        int row = i >> 8, d = i & 255;
        float4 a = *(const float4*)(cb + i);
        float4 b = *(const float4*)(cb + i + 4);
        float v[8] = {a.x, a.y, a.z, a.w, b.x, b.y, b.z, b.w};
        _Float16 h[8], l[8];
        #pragma unroll
        for (int k = 0; k < 8; k++) {
            h[k] = (_Float16)v[k];
            l[k] = (_Float16)(v[k] - (float)h[k]);   // v - (float)h is exact in fp32
        }
        *(f16x8*)(wpk + (size_t)row * 512 + d)       = *(const f16x8*)h;
        *(f16x8*)(wpk + (size_t)row * 512 + 256 + d) = *(const f16x8*)l;
    } else {
        // codebook squared norms (fp32 exact, bit-identical order): one wave/code
        int wid  = ((bid - 256) * 256 + t) >> 6;
        int lane = t & 63;
        const float4* c4 = (const float4*)cb;
        float4 v = c4[wid * 64 + lane];
        float s = v.x * v.x + v.y * v.y + v.z * v.z + v.w * v.w;
        #pragma unroll
        for (int m = 32; m >= 1; m >>= 1) s += __shfl_xor(s, m, 64);
        if (lane == 0) cbsq[wid] = s;
        if (bid == 256) {
            #pragma unroll
            for (int u = 0; u < 8; u++) usage[t * 8 + u] = 0;
            if (t == 0) { *accum = 0.0f; *ticket = 0; }
        }
    }
}

// -------- MFMA argmin (z staged as fp32, split in-reg) + gather + finalize -------
// 256 blocks x 512 thr (8 waves, 4x2). Block tile 256 rows x 2048 codes
// (8 chunks of 256), K-steps of 32. Double-buffered LDS + counted vmcnt(8)
// (the verified 198.7us schedule). A-tile staged as RAW fp32 from z (same
// 32 KB/step as fp16 h+l); h/l split done in-register per fragment with the
// bit-identical op sequence (h=(f16)v; l=(f16)(v-(float)h)) -> same MFMA
// inputs as the pre-split version, absmax preserved. Eliminates the whole
// 64MB z-split pre-pass (read+write) and the out-region aliasing.
// A LDS granule map: 16B granule gk of row r stored at slot ph = gk ^ (r&7);
// frag read at ph=(2q+b)^(rowT&7) returns k-slice [q*8+b*4), even bank spread.
// dot = zh*wh + zh*wl + zl*wh  (fp16 split; zl*wl term ~2^-24, dropped)
__global__ __launch_bounds__(512, 2)
void argmin_kernel(const float* __restrict__ z, const _Float16* __restrict__ wpk,
                   const float* __restrict__ cbsq, float* __restrict__ idx_out,
                   const float* __restrict__ cb, float* __restrict__ out,
                   int* __restrict__ usage, float* __restrict__ accum,
                   int* __restrict__ ticket, float* __restrict__ out2) {
    __shared__ float    Af[2][256 * 32];   // 2 x 32 KB fp32 A tile
    __shared__ _Float16 Bh[2][256 * 32];   // 2 x 16 KB
    __shared__ _Float16 Bl[2][256 * 32];   // 2 x 16 KB
    __shared__ float cbsq_lds[NCODES];     // 8 KB  -> total 136 KB
    __shared__ int amLast;

    const int t    = threadIdx.x;
    const int wave = t >> 6;
    const int lane = t & 63;
    const int quad = lane >> 4;
    const int l15  = lane & 15;
    const int wr0  = (wave >> 1) * 64;    // wave row offset within block tile
    const int wc0  = (wave & 1) * 128;    // wave code offset within chunk
    const int row0 = blockIdx.x * 256;

    // B swizzled read offset (granule of 8 halves): pos = quad ^ ((row>>1)&3)
    const int p8 = (quad ^ ((l15 >> 1) & 3)) * 8;

    // stage cbsq into LDS: 512 thr x 16 B = 8 KB
    ld16(cbsq + t * 4, &cbsq_lds[t * 4]);

    // stage one K=32 step: A fp32 (4 ld16) + Bh/Bl (2+2 ld16) = 8/thread
    #define STAGE(KC, CC, NB)                                                   \
        _Pragma("unroll")                                                       \
        for (int it = 0; it < 4; it++) {                                        \
            int s = it * 512 + t;                                               \
            int r = s >> 3;                                                     \
            int gk = (s & 7) ^ (r & 7);                                         \
            ld16(z + (size_t)(row0 + r) * 256 + (KC) * 32 + gk * 4,             \
                 &Af[NB][s * 4]);                                               \
        }                                                                       \
        _Pragma("unroll")                                                       \
        for (int it = 0; it < 2; it++) {                                        \
            int s = it * 512 + t;                                               \
            int r = s >> 2;                                                     \
            int g = (s & 3) ^ ((r >> 1) & 3);                                   \
            size_t offb = (size_t)((CC) * 256 + r) * 512 + (KC) * 32 + g * 8;   \
            ld16(wpk + offb,       &Bh[NB][s * 8]);                             \
            ld16(wpk + offb + 256, &Bl[NB][s * 8]);                             \
        }

    STAGE(0, 0, 0)   // prologue: step 0 into buffer 0

    float bd[16];
    int   bi[16];
    #pragma unroll
    for (int s = 0; s < 16; s++) { bd[s] = FLT_MAX; bi[s] = 0; }

    f32x4 acc[4][8];

    #pragma unroll 2
    for (int tt = 0; tt < 64; ++tt) {
        const int kc  = tt & 7;
        const int cur = tt & 1;

        // stage step tt+1 into the other buffer, then wait only for step tt's
        // 8 loads (issued one full compute-phase ago) -> latency hidden.
        if (tt < 63) {
            const int t1 = tt + 1;
            const int cc1 = t1 >> 3, kc1 = t1 & 7, nb = t1 & 1;
            STAGE(kc1, cc1, nb)
            asm volatile("s_waitcnt vmcnt(8)" ::: "memory");
        } else {
            asm volatile("s_waitcnt vmcnt(0)" ::: "memory");
        }
        __builtin_amdgcn_s_barrier();
        asm volatile("" ::: "memory");
        __builtin_amdgcn_sched_barrier(0);   // do not hoist ds_reads above barrier

        if (kc == 0) {
            #pragma unroll
            for (int i = 0; i < 4; i++)
                #pragma unroll
                for (int j = 0; j < 8; j++) acc[i][j] = (f32x4){0.f, 0.f, 0.f, 0.f};
        }

        const float*    Afc = &Af[cur][0];
        const _Float16* Bhc = &Bh[cur][0];
        const _Float16* Blc = &Bl[cur][0];

        // A frags: read fp32, split to h/l in-reg (bit-identical to split kernel)
        f16x8 ah[4], al[4];
        #pragma unroll
        for (int i = 0; i < 4; i++) {
            int rowT = wr0 + i * 16 + l15;
            int rb   = rowT * 32;
            int x7   = rowT & 7;
            f32x4 v0 = *(const f32x4*)&Afc[rb + (((quad << 1)    ) ^ x7) * 4];
            f32x4 v1 = *(const f32x4*)&Afc[rb + (((quad << 1) | 1) ^ x7) * 4];
            float vf[8] = {v0[0], v0[1], v0[2], v0[3], v1[0], v1[1], v1[2], v1[3]};
            _Float16 hh[8], ll[8];
            #pragma unroll
            for (int k = 0; k < 8; k++) {
                hh[k] = (_Float16)vf[k];
                ll[k] = (_Float16)(vf[k] - (float)hh[k]);   // exact in fp32
            }
            ah[i] = *(const f16x8*)hh;
            al[i] = *(const f16x8*)ll;
        }
        __builtin_amdgcn_s_setprio(1);
        #pragma unroll
        for (int j = 0; j < 8; j++) {
            int offb = (wc0 + j * 16 + l15) * 32 + p8;
            f16x8 bh = *(const f16x8*)&Bhc[offb];
            f16x8 bl = *(const f16x8*)&Blc[offb];
            #pragma unroll
            for (int i = 0; i < 4; i++) {
                acc[i][j] = __builtin_amdgcn_mfma_f32_16x16x32_f16(ah[i], bh, acc[i][j], 0, 0, 0);
                acc[i][j] = __builtin_amdgcn_mfma_f32_16x16x32_f16(ah[i], bl, acc[i][j], 0, 0, 0);
                acc[i][j] = __builtin_amdgcn_mfma_f32_16x16x32_f16(al[i], bh, acc[i][j], 0, 0, 0);
            }
        }
        __builtin_amdgcn_s_setprio(0);

        // epilogue each 8th step: d = cbsq[c] - 2*dot ; codes ascend -> first-min kept
        if (kc == 7) {
            const int cc = tt >> 3;
            #pragma unroll
            for (int j = 0; j < 8; j++) {
                int c = cc * 256 + wc0 + j * 16 + l15;
                float csq = cbsq_lds[c];
                #pragma unroll
                for (int i = 0; i < 4; i++) {
                    #pragma unroll
                    for (int r = 0; r < 4; r++) {
                        float d = fmaf(-2.0f, acc[i][j][r], csq);
                        int s = i * 4 + r;
                        if (d < bd[s]) { bd[s] = d; bi[s] = c; }
                    }
                }
            }
        }
        asm volatile("" ::: "memory");
        __builtin_amdgcn_s_barrier();
    }
    #undef STAGE

    // reduce across the 16 lanes (l15) holding the same rows; tie -> smaller index
    #pragma unroll
    for (int m = 1; m <= 8; m <<= 1) {
        #pragma unroll
        for (int s = 0; s < 16; s++) {
            float od = __shfl_xor(bd[s], m, 64);
            int   oi = __shfl_xor(bi[s], m, 64);
            if (od < bd[s] || (od == bd[s] && oi < bi[s])) { bd[s] = od; bi[s] = oi; }
        }
    }
    // overlay reduction arrays on LDS (all staging complete after the loop)
    float* rD = (float*)&Af[0][0];      // [2][256] floats
    int*   rI = (int*)&Af[0][1024];     // [2][256] ints (disjoint from rD)
    int*   sI = (int*)&Bh[0][0];        // [256] final per-row index
    if (l15 == 0) {
        const int wc = wave & 1;
        #pragma unroll
        for (int i = 0; i < 4; i++) {
            #pragma unroll
            for (int r = 0; r < 4; r++) {
                int row = wr0 + i * 16 + quad * 4 + r;
                rD[wc * 256 + row] = bd[i * 4 + r];
                rI[wc * 256 + row] = bi[i * 4 + r];
            }
        }
    }
    __syncthreads();
    if (t < 256) {
        float d0 = rD[t];       int i0 = rI[t];
        float d1 = rD[256 + t]; int i1 = rI[256 + t];
        int best = (d1 < d0 || (d1 == d0 && i1 < i0)) ? i1 : i0;
        sI[t] = best;
        idx_out[row0 + t] = (float)best;
    }
    __syncthreads();

    // -------- fused gather + STE + commitment partial + histogram --------
    {
        const float4* z4  = (const float4*)z;
        const float4* cb4 = (const float4*)cb;
        float4* o4 = (float4*)out;
        float local = 0.0f;
        for (int rr = wave; rr < 256; rr += 8) {
            int idx = sI[rr];
            size_t grow = (size_t)(row0 + rr);
            float4 zv = z4[grow * 64 + lane];
            float4 w  = cb4[(size_t)idx * 64 + lane];
            float4 d, o;
            d.x = w.x - zv.x; d.y = w.y - zv.y; d.z = w.z - zv.z; d.w = w.w - zv.w;
            o.x = zv.x + d.x; o.y = zv.y + d.y; o.z = zv.z + d.z; o.w = zv.w + d.w;
            o4[grow * 64 + lane] = o;
            local = fmaf(d.x, d.x, local);
            local = fmaf(d.y, d.y, local);
            local = fmaf(d.z, d.z, local);
            local = fmaf(d.w, d.w, local);
            if (lane == 0) atomicAdd(&usage[idx], 1);
        }
        #pragma unroll
        for (int m = 32; m >= 1; m >>= 1) local += __shfl_xor(local, m, 64);
        if (lane == 0) atomicAdd(accum, local);
    }

    // -------- last-block finalize: commitment mean + entropy loss --------
    // Drain this wave's outstanding (atomic) VMEM ops, then block barrier,
    // then one device-scope ticket RMW. No threadfence (R10-verified).
    asm volatile("s_waitcnt vmcnt(0)" ::: "memory");
    __syncthreads();
    if (t == 0) amLast = (atomicAdd(ticket, 1) == 255) ? 1 : 0;
    __syncthreads();
    if (amLast) {
        float* red = cbsq_lds;             // reuse (cbsq no longer needed)
        if (t < 256) {
            float e = 0.0f;
            for (int b = t; b < NCODES; b += 256) {
                // atomic read -> device-coherent across XCD L2s
                float p = (float)atomicAdd(&usage[b], 0) * (1.0f / 65536.0f);
                e -= p * logf(p + 1e-10f);
            }
            red[t] = e;
        }
        __syncthreads();
        if (t == 0) {
            float s = 0.0f;
            for (int k = 0; k < 256; k++) s += red[k];
            out2[0] = atomicAdd(accum, 0.0f) / 16777216.0f;
            out2[1] = logf(2048.0f) - s;
        }
    }
}

extern "C" void kernel_launch(void* const* d_in, const int* in_sizes, int n_in,
                              void* d_out, int out_size, void* d_ws, size_t ws_size,
                              hipStream_t stream) {
    const float* z  = (const float*)d_in[0];
    const float* cb = (const float*)d_in[1];

    float* out   = (float*)d_out;
    float* idx_f = out + (size_t)NROWS * DIM;   // float offset 16777216 (byte 67108864)
    float* out2  = idx_f + NROWS;

    // ws: wpk 2MB (interleaved h|l per code) | cbsq 8KB | usage 8KB | accum | ticket
    _Float16* wpk  = (_Float16*)d_ws;
    float*    cbsq = (float*)((char*)d_ws + 2097152);
    int*      usage= (int*)((char*)d_ws + 2105344);
    float*    accum= (float*)((char*)d_ws + 2113536);
    int*      ticket=(int*)((char*)d_ws + 2113540);

    prep_kernel<<<768, 256, 0, stream>>>(cb, wpk, cbsq, usage, accum, ticket);
    argmin_kernel<<<256, 512, 0, stream>>>(z, wpk, cbsq, idx_f, cb, out, usage,
                                           accum, ticket, out2);
}